// Round 6
// baseline (520.783 us; speedup 1.0000x reference)
//
#include <hip/hip_runtime.h>

#define N_NODES 100000
#define N_EDGES 1600000
#define D 128
#define SCAN_BLK 1024
#define NB_SCAN 98   // ceil(100000/1024)
#define GATHER_SLOTS 8

// ---------------- threefry2x32 (exact JAX semantics) ----------------
struct KeyPair { unsigned a, b; };

__host__ __device__ constexpr unsigned rotl32c(unsigned x, int d) {
    return (x << d) | (x >> (32 - d));
}

__host__ __device__ constexpr KeyPair threefry2x32(unsigned k0, unsigned k1,
                                                   unsigned x0, unsigned x1) {
    unsigned ks0 = k0, ks1 = k1, ks2 = 0x1BD11BDAu ^ k0 ^ k1;
    const int rot0[4] = {13, 15, 26, 6};
    const int rot1[4] = {17, 29, 16, 24};
    x0 += ks0; x1 += ks1;
    for (int i = 0; i < 4; ++i) { x0 += x1; x1 = rotl32c(x1, rot0[i]); x1 ^= x0; }
    x0 += ks1; x1 += ks2 + 1u;
    for (int i = 0; i < 4; ++i) { x0 += x1; x1 = rotl32c(x1, rot1[i]); x1 ^= x0; }
    x0 += ks2; x1 += ks0 + 2u;
    for (int i = 0; i < 4; ++i) { x0 += x1; x1 = rotl32c(x1, rot0[i]); x1 ^= x0; }
    x0 += ks0; x1 += ks1 + 3u;
    for (int i = 0; i < 4; ++i) { x0 += x1; x1 = rotl32c(x1, rot1[i]); x1 ^= x0; }
    x0 += ks1; x1 += ks2 + 4u;
    for (int i = 0; i < 4; ++i) { x0 += x1; x1 = rotl32c(x1, rot0[i]); x1 ^= x0; }
    x0 += ks2; x1 += ks0 + 5u;
    return {x0, x1};
}

constexpr KeyPair FKEY = threefry2x32(0u, 42u, 0u, 7u);

// partitionable threefry bits: b1^b2 of threefry(key, (0, e))
__device__ __forceinline__ float dropout_val(float xv, unsigned e) {
    KeyPair o = threefry2x32(FKEY.a, FKEY.b, 0u, e);
    unsigned bits = o.a ^ o.b;
    float u = __uint_as_float((bits >> 9) | 0x3f800000u) - 1.0f;
    return (u < 0.9f) ? xv * (1.0f / 0.9f) : 0.0f;
}

// ---------------- kernel: fused dropout + [N,128]@[128,128] ----------------
// 4 rows x 2 cols per thread: 4 broadcast LDS reads + 1 float2 w load per 8 FMAs
__global__ __launch_bounds__(256) void gemm_dropout_kernel(
        const float* __restrict__ x, const float* __restrict__ w,
        float* __restrict__ h) {
    __shared__ float xs[16][128];
    const int t = threadIdx.x;
    const int base = blockIdx.x * (16 * 128);

    #pragma unroll
    for (int i = 0; i < 8; ++i) {
        int idx = t + i * 256;
        float xv = x[base + idx];
        xs[idx >> 7][idx & 127] = dropout_val(xv, (unsigned)(base + idx));
    }
    __syncthreads();

    const int col = (t & 63) * 2;
    const int g = t >> 6;           // 0..3 -> rows g*4..g*4+3 (uniform per wave)
    float acc[4][2] = {};

    #pragma unroll 2
    for (int k = 0; k < 128; ++k) {
        const float2 wv = *reinterpret_cast<const float2*>(&w[k * 128 + col]);
        #pragma unroll
        for (int i = 0; i < 4; ++i) {
            float xv = xs[g * 4 + i][k];
            acc[i][0] += xv * wv.x;
            acc[i][1] += xv * wv.y;
        }
    }

    const int row0 = blockIdx.x * 16 + g * 4;
    #pragma unroll
    for (int i = 0; i < 4; ++i) {
        float2 o; o.x = acc[i][0]; o.y = acc[i][1];
        *reinterpret_cast<float2*>(&h[(row0 + i) * 128 + col]) = o;
    }
}

// ---------------- CSR build: histogram -> scan -> counting sort ----------------
__global__ __launch_bounds__(256) void hist_kernel(
        const int* __restrict__ edst, int* __restrict__ counts) {
    int e = blockIdx.x * 256 + threadIdx.x;
    if (e < N_EDGES) atomicAdd(&counts[edst[e]], 1);
}

__global__ __launch_bounds__(SCAN_BLK) void partial_kernel(
        const int* __restrict__ counts, int* __restrict__ partials) {
    __shared__ int sdata[SCAN_BLK];
    int idx = blockIdx.x * SCAN_BLK + threadIdx.x;
    sdata[threadIdx.x] = (idx < N_NODES) ? counts[idx] : 0;
    __syncthreads();
    for (int s = SCAN_BLK / 2; s > 0; s >>= 1) {
        if (threadIdx.x < s) sdata[threadIdx.x] += sdata[threadIdx.x + s];
        __syncthreads();
    }
    if (threadIdx.x == 0) partials[blockIdx.x] = sdata[0];
}

__global__ void scanpartials_kernel(int* __restrict__ partials) {
    if (threadIdx.x == 0) {
        int run = 0;
        for (int b = 0; b < NB_SCAN; ++b) {
            int t = partials[b];
            partials[b] = run;
            run += t;
        }
    }
}

__global__ __launch_bounds__(SCAN_BLK) void finalize_kernel(
        const int* __restrict__ counts, const int* __restrict__ partials,
        int* __restrict__ offsets, int* __restrict__ cursor) {
    __shared__ int sc[SCAN_BLK];
    int idx = blockIdx.x * SCAN_BLK + threadIdx.x;
    int v = (idx < N_NODES) ? counts[idx] : 0;
    sc[threadIdx.x] = v;
    __syncthreads();
    // Hillis-Steele inclusive scan
    for (int off = 1; off < SCAN_BLK; off <<= 1) {
        int t = (threadIdx.x >= off) ? sc[threadIdx.x - off] : 0;
        __syncthreads();
        sc[threadIdx.x] += t;
        __syncthreads();
    }
    if (idx < N_NODES) {
        int base = partials[blockIdx.x];
        int excl = base + sc[threadIdx.x] - v;
        offsets[idx] = excl;
        cursor[idx] = excl;
        if (idx == N_NODES - 1) offsets[N_NODES] = base + sc[threadIdx.x];
    }
}

__global__ __launch_bounds__(256) void sort_kernel(
        const int* __restrict__ esrc, const int* __restrict__ edst,
        const float* __restrict__ evals, int* __restrict__ cursor,
        int2* __restrict__ spack) {
    int e = blockIdx.x * 256 + threadIdx.x;
    if (e < N_EDGES) {
        int d = edst[e];
        int pos = atomicAdd(&cursor[d], 1);
        int2 p;
        p.x = esrc[e];
        p.y = __float_as_int(evals[e]);
        spack[pos] = p;   // single 8B store per edge
    }
}

// ---------------- gather + fused ReLU (8 edge-slots x 32 lanes x float4) ----
__global__ __launch_bounds__(256) void gather_kernel(
        const float* __restrict__ h, const int* __restrict__ offsets,
        const int2* __restrict__ spack, float* __restrict__ out) {
    __shared__ float red[GATHER_SLOTS][128];
    const int node = blockIdx.x;
    const int t = threadIdx.x;
    const int s = t >> 5;        // edge slot 0..7
    const int lane = t & 31;
    const int d4 = lane * 4;
    const int start = offsets[node];
    const int end = offsets[node + 1];

    float a0 = 0.f, a1 = 0.f, a2 = 0.f, a3 = 0.f;
    for (int j = start + s; j < end; j += GATHER_SLOTS) {
        int2 p = spack[j];
        float val = __int_as_float(p.y);
        const float4 hv = *reinterpret_cast<const float4*>(h + (size_t)p.x * 128 + d4);
        a0 += val * hv.x;
        a1 += val * hv.y;
        a2 += val * hv.z;
        a3 += val * hv.w;
    }
    float4 r; r.x = a0; r.y = a1; r.z = a2; r.w = a3;
    *reinterpret_cast<float4*>(&red[s][d4]) = r;
    __syncthreads();

    if (t < 128) {
        float acc = 0.f;
        #pragma unroll
        for (int ss = 0; ss < GATHER_SLOTS; ++ss) acc += red[ss][t];
        out[node * 128 + t] = fmaxf(acc, 0.f);
    }
}

extern "C" void kernel_launch(void* const* d_in, const int* in_sizes, int n_in,
                              void* d_out, int out_size, void* d_ws, size_t ws_size,
                              hipStream_t stream) {
    const float* x     = (const float*)d_in[0];
    const float* w     = (const float*)d_in[1];
    const int*   esrc  = (const int*)d_in[2];
    const int*   edst  = (const int*)d_in[3];
    const float* evals = (const float*)d_in[4];
    float* out = (float*)d_out;

    char* ws = (char*)d_ws;
    float* h        = (float*)(ws);                 // 51,200,000 B
    int*   counts   = (int*)(ws + 51200000);        //    400,000 B
    int*   offsets  = (int*)(ws + 51600000);        //    400,128 B (100001 ints)
    int*   cursor   = (int*)(ws + 52000128);        //    400,000 B
    int2*  spack    = (int2*)(ws + 52400128);       // 12,800,000 B (8B-aligned)
    int*   partials = (int*)(ws + 65200128);        //        512 B

    // zero only the histogram (ws is poisoned 0xAA each call)
    hipMemsetAsync(counts, 0, N_NODES * sizeof(int), stream);

    // CSR build
    hist_kernel<<<(N_EDGES + 255) / 256, 256, 0, stream>>>(edst, counts);
    partial_kernel<<<NB_SCAN, SCAN_BLK, 0, stream>>>(counts, partials);
    scanpartials_kernel<<<1, 64, 0, stream>>>(partials);
    finalize_kernel<<<NB_SCAN, SCAN_BLK, 0, stream>>>(counts, partials, offsets, cursor);
    sort_kernel<<<(N_EDGES + 255) / 256, 256, 0, stream>>>(esrc, edst, evals, cursor, spack);

    // dense transform
    gemm_dropout_kernel<<<N_NODES / 16, 256, 0, stream>>>(x, w, h);

    // aggregate + ReLU (writes every output element; no d_out memset needed)
    gather_kernel<<<N_NODES, 256, 0, stream>>>(h, offsets, spack, out);
}

// Round 7
// 450.360 us; speedup vs baseline: 1.1564x; 1.1564x over previous
//
#include <hip/hip_runtime.h>

#define N_NODES 100000
#define N_EDGES 1600000
#define SCAN_BLK 1024
#define NB_SCAN 98   // ceil(100000/1024)
#define GATHER_SLOTS 8

typedef short bf16x8 __attribute__((ext_vector_type(8)));
typedef float f32x4 __attribute__((ext_vector_type(4)));

// ---------------- threefry2x32 (exact JAX semantics) ----------------
struct KeyPair { unsigned a, b; };

__host__ __device__ constexpr unsigned rotl32c(unsigned x, int d) {
    return (x << d) | (x >> (32 - d));
}

__host__ __device__ constexpr KeyPair threefry2x32(unsigned k0, unsigned k1,
                                                   unsigned x0, unsigned x1) {
    unsigned ks0 = k0, ks1 = k1, ks2 = 0x1BD11BDAu ^ k0 ^ k1;
    const int rot0[4] = {13, 15, 26, 6};
    const int rot1[4] = {17, 29, 16, 24};
    x0 += ks0; x1 += ks1;
    for (int i = 0; i < 4; ++i) { x0 += x1; x1 = rotl32c(x1, rot0[i]); x1 ^= x0; }
    x0 += ks1; x1 += ks2 + 1u;
    for (int i = 0; i < 4; ++i) { x0 += x1; x1 = rotl32c(x1, rot1[i]); x1 ^= x0; }
    x0 += ks2; x1 += ks0 + 2u;
    for (int i = 0; i < 4; ++i) { x0 += x1; x1 = rotl32c(x1, rot0[i]); x1 ^= x0; }
    x0 += ks0; x1 += ks1 + 3u;
    for (int i = 0; i < 4; ++i) { x0 += x1; x1 = rotl32c(x1, rot1[i]); x1 ^= x0; }
    x0 += ks1; x1 += ks2 + 4u;
    for (int i = 0; i < 4; ++i) { x0 += x1; x1 = rotl32c(x1, rot0[i]); x1 ^= x0; }
    x0 += ks2; x1 += ks0 + 5u;
    return {x0, x1};
}

constexpr KeyPair FKEY = threefry2x32(0u, 42u, 0u, 7u);

// partitionable threefry bits: b1^b2 of threefry(key, (0, e))
__device__ __forceinline__ float dropout_val(float xv, unsigned e) {
    KeyPair o = threefry2x32(FKEY.a, FKEY.b, 0u, e);
    unsigned bits = o.a ^ o.b;
    float u = __uint_as_float((bits >> 9) | 0x3f800000u) - 1.0f;
    return (u < 0.9f) ? xv * (1.0f / 0.9f) : 0.0f;
}

// fp32 -> bf16 RTNE
__device__ __forceinline__ unsigned short f2bf(float f) {
    unsigned u = __float_as_uint(f);
    unsigned r = (u + 0x7FFFu + ((u >> 16) & 1u)) >> 16;
    return (unsigned short)r;
}

// ---------------- W -> bf16, transposed + XOR-swizzled (wt[n][k]) ----------
__global__ __launch_bounds__(256) void wconv_kernel(
        const float* __restrict__ w, char* __restrict__ wt) {
    int id = blockIdx.x * 256 + threadIdx.x;   // 16384 = 128*128
    int k = id >> 7;
    int n = id & 127;
    unsigned short b = f2bf(w[k * 128 + n]);
    unsigned byte = ((unsigned)(n * 256 + k * 2)) ^ ((unsigned)((n & 7) << 4));
    *(unsigned short*)(wt + byte) = b;
}

// ---------------- fused dropout + MFMA GEMM, h in bf16 ----------------
// block = 256 threads (4 waves), tile = 64 rows x 128 cols
__global__ __launch_bounds__(256) void gemm_dropout_kernel(
        const float* __restrict__ x, const char* __restrict__ wt,
        unsigned short* __restrict__ h) {
    __shared__ __align__(16) char smem[49152];  // [0,16K): A 64x128 bf16 swz; [16K,48K): B^T swz
    const int t = threadIdx.x;
    const int r0 = blockIdx.x * 64;

    // stage B: 32KB linear copy (lanes consecutive 16B -> conflict-free, coalesced)
    #pragma unroll
    for (int i = 0; i < 8; ++i) {
        int off = t * 16 + i * 4096;
        *(uint4*)(smem + 16384 + off) = *(const uint4*)(wt + off);
    }

    // stage A: load 64x128 x-tile, dropout, bf16, swizzled LDS write
    {
        const int row = t >> 2;           // 0..63
        const int ks  = (t & 3) * 32;     // k segment
        const int grow = r0 + row;
        const bool valid = grow < N_NODES;
        float xv[32];
        #pragma unroll
        for (int q = 0; q < 8; ++q) {
            float4 v = valid ? *(const float4*)(x + (size_t)grow * 128 + ks + q * 4)
                             : make_float4(0.f, 0.f, 0.f, 0.f);
            xv[q * 4 + 0] = v.x; xv[q * 4 + 1] = v.y;
            xv[q * 4 + 2] = v.z; xv[q * 4 + 3] = v.w;
        }
        const unsigned ebase = (unsigned)grow * 128u + (unsigned)ks;
        #pragma unroll
        for (int q = 0; q < 4; ++q) {
            unsigned pk[4];
            #pragma unroll
            for (int p = 0; p < 4; ++p) {
                float a = dropout_val(xv[q * 8 + p * 2],     ebase + q * 8 + p * 2);
                float b = dropout_val(xv[q * 8 + p * 2 + 1], ebase + q * 8 + p * 2 + 1);
                pk[p] = (unsigned)f2bf(a) | ((unsigned)f2bf(b) << 16);
            }
            unsigned byte = ((unsigned)(row * 256 + (ks + q * 8) * 2))
                            ^ ((unsigned)((row & 7) << 4));
            *(uint4*)(smem + byte) = *(uint4*)pk;
        }
    }
    __syncthreads();

    // MFMA: wave wv computes rows r0+wv*16..+15 x all 128 cols
    const int wv = t >> 6;
    const int l  = t & 63;
    const int lm = l & 15;
    const int lg = l >> 4;
    const int arow = wv * 16 + lm;
    const unsigned axor = (unsigned)((arow & 7) << 4);
    const unsigned aoff = (unsigned)(arow * 256 + lg * 16);
    const unsigned bxor = (unsigned)((lm & 7) << 4);
    const unsigned boff = (unsigned)(lm * 256 + lg * 16);

    f32x4 acc[8] = {};
    #pragma unroll
    for (int kc = 0; kc < 4; ++kc) {
        bf16x8 af = *(const bf16x8*)(smem + ((aoff + kc * 64) ^ axor));
        #pragma unroll
        for (int nt = 0; nt < 8; ++nt) {
            bf16x8 bf = *(const bf16x8*)(smem + 16384 + nt * 4096
                                         + ((boff + kc * 64) ^ bxor));
            acc[nt] = __builtin_amdgcn_mfma_f32_16x16x32_bf16(af, bf, acc[nt], 0, 0, 0);
        }
    }

    // epilogue: C/D layout col=lane&15, row=(lane>>4)*4+reg  [verified m89]
    const int orow0 = r0 + wv * 16 + lg * 4;
    #pragma unroll
    for (int nt = 0; nt < 8; ++nt) {
        const int col = nt * 16 + lm;
        #pragma unroll
        for (int r2 = 0; r2 < 4; ++r2) {
            const int row = orow0 + r2;
            if (row < N_NODES) h[(size_t)row * 128 + col] = f2bf(acc[nt][r2]);
        }
    }
}

// ---------------- CSR build: histogram -> scan -> counting sort ----------------
__global__ __launch_bounds__(256) void hist_kernel(
        const int* __restrict__ edst, int* __restrict__ counts) {
    int e = blockIdx.x * 256 + threadIdx.x;
    if (e < N_EDGES) atomicAdd(&counts[edst[e]], 1);
}

__global__ __launch_bounds__(SCAN_BLK) void partial_kernel(
        const int* __restrict__ counts, int* __restrict__ partials) {
    __shared__ int sdata[SCAN_BLK];
    int idx = blockIdx.x * SCAN_BLK + threadIdx.x;
    sdata[threadIdx.x] = (idx < N_NODES) ? counts[idx] : 0;
    __syncthreads();
    for (int s = SCAN_BLK / 2; s > 0; s >>= 1) {
        if (threadIdx.x < s) sdata[threadIdx.x] += sdata[threadIdx.x + s];
        __syncthreads();
    }
    if (threadIdx.x == 0) partials[blockIdx.x] = sdata[0];
}

__global__ void scanpartials_kernel(int* __restrict__ partials) {
    if (threadIdx.x == 0) {
        int run = 0;
        for (int b = 0; b < NB_SCAN; ++b) {
            int t = partials[b];
            partials[b] = run;
            run += t;
        }
    }
}

__global__ __launch_bounds__(SCAN_BLK) void finalize_kernel(
        const int* __restrict__ counts, const int* __restrict__ partials,
        int* __restrict__ offsets, int* __restrict__ cursor) {
    __shared__ int sc[SCAN_BLK];
    int idx = blockIdx.x * SCAN_BLK + threadIdx.x;
    int v = (idx < N_NODES) ? counts[idx] : 0;
    sc[threadIdx.x] = v;
    __syncthreads();
    for (int off = 1; off < SCAN_BLK; off <<= 1) {
        int t = (threadIdx.x >= off) ? sc[threadIdx.x - off] : 0;
        __syncthreads();
        sc[threadIdx.x] += t;
        __syncthreads();
    }
    if (idx < N_NODES) {
        int base = partials[blockIdx.x];
        int excl = base + sc[threadIdx.x] - v;
        offsets[idx] = excl;
        cursor[idx] = excl;
        if (idx == N_NODES - 1) offsets[N_NODES] = base + sc[threadIdx.x];
    }
}

__global__ __launch_bounds__(256) void sort_kernel(
        const int* __restrict__ esrc, const int* __restrict__ edst,
        const float* __restrict__ evals, int* __restrict__ cursor,
        int2* __restrict__ spack) {
    int e = blockIdx.x * 256 + threadIdx.x;
    if (e < N_EDGES) {
        int d = edst[e];
        int pos = atomicAdd(&cursor[d], 1);
        int2 p;
        p.x = esrc[e];
        p.y = __float_as_int(evals[e]);
        spack[pos] = p;
    }
}

// ---------------- gather + fused ReLU (bf16 h, 8 slots x 32 lanes x 4 dims) --
__global__ __launch_bounds__(256) void gather_kernel(
        const unsigned short* __restrict__ h, const int* __restrict__ offsets,
        const int2* __restrict__ spack, float* __restrict__ out) {
    __shared__ float red[GATHER_SLOTS][128];
    const int node = blockIdx.x;
    const int t = threadIdx.x;
    const int s = t >> 5;
    const int lane = t & 31;
    const int d4 = lane * 4;
    const int start = offsets[node];
    const int end = offsets[node + 1];

    float a0 = 0.f, a1 = 0.f, a2 = 0.f, a3 = 0.f;
    for (int j = start + s; j < end; j += GATHER_SLOTS) {
        int2 p = spack[j];
        float val = __int_as_float(p.y);
        uint2 hv = *(const uint2*)(h + (size_t)p.x * 128 + d4);
        float h0 = __uint_as_float((hv.x & 0xFFFFu) << 16);
        float h1 = __uint_as_float(hv.x & 0xFFFF0000u);
        float h2 = __uint_as_float((hv.y & 0xFFFFu) << 16);
        float h3 = __uint_as_float(hv.y & 0xFFFF0000u);
        a0 += val * h0; a1 += val * h1; a2 += val * h2; a3 += val * h3;
    }
    float4 r; r.x = a0; r.y = a1; r.z = a2; r.w = a3;
    *reinterpret_cast<float4*>(&red[s][d4]) = r;
    __syncthreads();

    if (t < 128) {
        float acc = 0.f;
        #pragma unroll
        for (int ss = 0; ss < GATHER_SLOTS; ++ss) acc += red[ss][t];
        out[node * 128 + t] = fmaxf(acc, 0.f);
    }
}

extern "C" void kernel_launch(void* const* d_in, const int* in_sizes, int n_in,
                              void* d_out, int out_size, void* d_ws, size_t ws_size,
                              hipStream_t stream) {
    const float* x     = (const float*)d_in[0];
    const float* w     = (const float*)d_in[1];
    const int*   esrc  = (const int*)d_in[2];
    const int*   edst  = (const int*)d_in[3];
    const float* evals = (const float*)d_in[4];
    float* out = (float*)d_out;

    char* ws = (char*)d_ws;
    unsigned short* h        = (unsigned short*)(ws);      // 25,600,000 B (bf16)
    int*            counts   = (int*)(ws + 25600000);      //    400,000 B
    int*            offsets  = (int*)(ws + 26000000);      //    400,128 B
    int*            cursor   = (int*)(ws + 26400128);      //    400,000 B
    int2*           spack    = (int2*)(ws + 26800128);     // 12,800,000 B
    int*            partials = (int*)(ws + 39600128);      //        512 B
    char*           wt       = (char*)(ws + 39600640);     //     32,768 B

    hipMemsetAsync(counts, 0, N_NODES * sizeof(int), stream);

    // CSR build
    hist_kernel<<<(N_EDGES + 255) / 256, 256, 0, stream>>>(edst, counts);
    partial_kernel<<<NB_SCAN, SCAN_BLK, 0, stream>>>(counts, partials);
    scanpartials_kernel<<<1, 64, 0, stream>>>(partials);
    finalize_kernel<<<NB_SCAN, SCAN_BLK, 0, stream>>>(counts, partials, offsets, cursor);
    sort_kernel<<<(N_EDGES + 255) / 256, 256, 0, stream>>>(esrc, edst, evals, cursor, spack);

    // dense transform (bf16 MFMA)
    wconv_kernel<<<64, 256, 0, stream>>>(w, wt);
    gemm_dropout_kernel<<<(N_NODES + 63) / 64, 256, 0, stream>>>(x, wt, h);

    // aggregate + ReLU
    gather_kernel<<<N_NODES, 256, 0, stream>>>(h, offsets, spack, out);
}